// Round 11
// baseline (92.941 us; speedup 1.0000x reference)
//
#include <hip/hip_runtime.h>
#include <hip/hip_bf16.h>

#define B_  8
#define L_  4096
#define DH  64

typedef __attribute__((ext_vector_type(8)))  __bf16 bf16x8;
typedef __attribute__((ext_vector_type(16))) float  f32x16;
typedef __attribute__((ext_vector_type(4)))  float  f32x4;
typedef __attribute__((ext_vector_type(8)))  unsigned short u16x8;

// workspace offsets (u16 units unless noted)
#define QW_OFF  0u
#define KW_OFF  2097152u      // Kp: plain 32-row K images [8][128][2048]
#define VP_OFF  4194304u      // Vp: slot-permuted V images [8][128][2048]
#define OP_OFF  6291456u      // bf16 partials [8][32][8][128][64]
#define LP_OFFB 46137344u     // byte offset: f32 l partials [8][32][8][128]

// ---------------------------------------------------------------------------
// Kernel 1: MFMA QKV projection (round-5 verified structure; K/V images now
// stored WITHOUT the LDS-bank XOR swizzles — attn reads them from global).
//   qo row-major [B*L][64]  (pre-scaled by log2e/sqrt(65))
//   Kp: plain 32-row tiles [32][64]
//   Vp: 32-kv tiles [dv][32], chunk cp holds kv = (cp>>1)*16 + (cp&1)*4
//       + (j&3) + 8*(j>>2)  (MFMA slot bijection, no XOR)
// ---------------------------------------------------------------------------
__global__ __launch_bounds__(256) void qkv_proj(
    const float* __restrict__ x,
    const float* __restrict__ Wq, const float* __restrict__ bq,
    const float* __restrict__ Wk, const float* __restrict__ bk,
    const float* __restrict__ Wv, const float* __restrict__ bv,
    unsigned short* __restrict__ qo,
    unsigned short* __restrict__ Kp,
    unsigned short* __restrict__ Vp)
{
    __shared__ __align__(16) unsigned short xs[64 * 104];
    __shared__ __align__(16) unsigned short wt[64 * 104];
    __shared__ __align__(16) unsigned short bounce[64 * 64];
    __shared__ float bsm[64];

    const int tid = threadIdx.x;
    const int r0  = blockIdx.x * 64;
    const int bb  = r0 >> 12;
    const int l0  = r0 & 4095;

    {   // zero (pads must stay 0 for the k=64..95 MFMA step)
        const u16x8 z = {0,0,0,0,0,0,0,0};
        for (int i = tid; i < (64 * 104) / 8; i += 256) {
            ((u16x8*)xs)[i] = z;  ((u16x8*)wt)[i] = z;
        }
    }
    __syncthreads();

    // stage x -> bf16 LDS, coalesced
    for (int i = tid; i < 64 * 65; i += 256) {
        const int row = i / 65, col = i - row * 65;
        __hip_bfloat16 v = __float2bfloat16(x[(size_t)r0 * 65 + i]);
        xs[row * 104 + col] = *(unsigned short*)&v;
    }

    const float* Wp[3] = {Wq, Wk, Wv};
    const float* bp[3] = {bq, bk, bv};

    const int w = tid >> 6, lane = tid & 63, li = lane & 15, lg = lane >> 4;
    const int rb = w * 16;

#pragma unroll
    for (int p = 0; p < 3; ++p) {
        __syncthreads();                       // prior pass done with wt/bounce
        for (int i = tid; i < 65 * 64; i += 256) {
            const int k = i >> 6, cc = i & 63;
            __hip_bfloat16 v = __float2bfloat16(Wp[p][i]);
            wt[cc * 104 + k] = *(unsigned short*)&v;
        }
        if (tid < 64) bsm[tid] = bp[p][tid];
        __syncthreads();

        f32x4 acc[4];
#pragma unroll
        for (int j = 0; j < 4; ++j) {
            const float bv_ = bsm[j * 16 + li];
            acc[j] = (f32x4){bv_, bv_, bv_, bv_};
        }
#pragma unroll
        for (int ks = 0; ks < 3; ++ks) {
            const bf16x8 a = __builtin_bit_cast(bf16x8,
                *(const u16x8*)&xs[(rb + li) * 104 + ks * 32 + 8 * lg]);
#pragma unroll
            for (int j = 0; j < 4; ++j) {
                const bf16x8 bf = __builtin_bit_cast(bf16x8,
                    *(const u16x8*)&wt[(j * 16 + li) * 104 + ks * 32 + 8 * lg]);
                acc[j] = __builtin_amdgcn_mfma_f32_16x16x32_bf16(a, bf, acc[j], 0, 0, 0);
            }
        }

        // acc -> bounce (bf16), D row = rb + lg*4 + r, col = j*16 + li
        const float scale = (p == 0) ? (1.4426950408889634f / 8.06225774829855f) : 1.0f;
#pragma unroll
        for (int j = 0; j < 4; ++j)
#pragma unroll
            for (int r = 0; r < 4; ++r) {
                __hip_bfloat16 hv = __float2bfloat16(acc[j][r] * scale);
                bounce[(rb + lg * 4 + r) * 64 + j * 16 + li] = *(unsigned short*)&hv;
            }
        __syncthreads();

        if (p == 0) {
            const int row = tid >> 2, col = (tid & 3) * 16;
            unsigned short* op = qo + (size_t)(r0 + row) * 64 + col;
            *(u16x8*)op       = *(const u16x8*)&bounce[row * 64 + col];
            *(u16x8*)(op + 8) = *(const u16x8*)&bounce[row * 64 + col + 8];
        } else if (p == 1) {
#pragma unroll
            for (int e = 0; e < 2; ++e) {
                const int pi = tid * 2 + e;
                const int row = pi >> 3, s = pi & 7;
                const int l = l0 + row;
                const u16x8 piece = *(const u16x8*)&bounce[row * 64 + (s << 3)];
                *(u16x8*)(Kp + (size_t)(bb * 128 + (l >> 5)) * 2048 + (l & 31) * 64 + s * 8) = piece;
            }
        } else {
#pragma unroll
            for (int e = 0; e < 2; ++e) {
                const int pi = tid * 2 + e;
                const int t32 = pi >> 8, rem = pi & 255;
                const int dv = rem >> 2, cp = rem & 3;
                const int m = cp >> 1, hh = cp & 1;
                u16x8 piece;
#pragma unroll
                for (int j = 0; j < 8; ++j) {
                    const int kv = m * 16 + hh * 4 + (j & 3) + 8 * (j >> 2);
                    piece[j] = bounce[(t32 * 32 + kv) * 64 + dv];
                }
                *(u16x8*)(Vp + (size_t)(bb * 128 + (l0 >> 5) + t32) * 2048 + dv * 32 + cp * 8) = piece;
            }
        }
    }
}

// ---------------------------------------------------------------------------
// Kernel 2: causal flash attention — barrier-free, LDS-free.
// 32x32x16 MFMA, fixed softmax base M=8. Block = (b, 128 q, 512-kv chunk),
// 4 autonomous waves x 32 q. K/V fragments read DIRECTLY from the dense
// global tile images (L1/L2-resident; batch pinned to XCD by b=blockIdx&7),
// with a one-sub register prefetch. No __syncthreads, no LDS, no vmcnt.
// ---------------------------------------------------------------------------
__global__ __launch_bounds__(256) void attn(
    const unsigned short* __restrict__ Q,
    const unsigned short* __restrict__ Kp,
    const unsigned short* __restrict__ Vp,
    float* __restrict__ O,
    unsigned short* __restrict__ Op,
    float* __restrict__ Lp)
{
    const int tid  = threadIdx.x;
    const int w    = tid >> 6;
    const int lane = tid & 63;
    const int li32 = lane & 31;
    const int h    = lane >> 5;

    const int b = blockIdx.x & 7;
    const int p = 143 - (blockIdx.x >> 3);   // heavy chunks first
    int g = 0;
    while (2 * (g + 1) * (g + 2) <= p) ++g;
    const int id2 = p - 2 * g * (g + 1);
    const int qq  = id2 / (g + 1);
    const int qb  = 4 * g + qq;
    const int c   = id2 - qq * (g + 1);

    const int q0    = qb * 128;
    const int kv0   = c << 9;
    const int kvend = (kv0 + 512 < q0 + 128) ? kv0 + 512 : q0 + 128;
    const int nsub  = (kvend - kv0) >> 5;          // 32-kv sub-tiles in chunk
    const int q0w   = q0 + w * 32;
    const int q     = q0w + li32;
    const int sdiag = (q0w - kv0) >> 5;            // diagonal sub index
    const int ns    = (sdiag + 1 < nsub) ? sdiag + 1 : nsub;

    const size_t base = (size_t)b * L_ * DH;
    // per-lane fragment bases (sub-tile stride = 2048 u16 = one 32-kv image)
    const unsigned short* kbase =
        Kp + ((size_t)(b * 128) + (kv0 >> 5)) * 2048 + li32 * 64 + h * 8;
    const unsigned short* vbase =
        Vp + ((size_t)(b * 128) + (kv0 >> 5)) * 2048 + li32 * 32 + h * 8;

    // Q fragments: B-operand, col = q, slot (h,j) -> d = ks*16 + h*8 + j
    bf16x8 qf[4];
#pragma unroll
    for (int ks = 0; ks < 4; ++ks)
        qf[ks] = __builtin_bit_cast(bf16x8,
            *(const u16x8*)(Q + base + (size_t)q * DH + ks * 16 + h * 8));

    // all-ones B fragment for the row-sum MFMA
    u16x8 ou;
#pragma unroll
    for (int i = 0; i < 8; ++i) ou[i] = 0x3F80;
    const bf16x8 ones = __builtin_bit_cast(bf16x8, ou);

    f32x16 o0, o1, l_acc;
#pragma unroll
    for (int r = 0; r < 16; ++r) { o0[r] = 0.0f; o1[r] = 0.0f; l_acc[r] = 0.0f; }

    // prefetch sub 0: K fragments at chunk (ks<<1)|h -> byte off ks*32 from base
    u16x8 kf[4], vf[4];
#pragma unroll
    for (int ks = 0; ks < 4; ++ks) kf[ks] = *(const u16x8*)(kbase + ks * 16);
    vf[0] = *(const u16x8*)(vbase);               // dv=li32,    chunk h
    vf[1] = *(const u16x8*)(vbase + 16);          // dv=li32,    chunk 2+h
    vf[2] = *(const u16x8*)(vbase + 1024);        // dv=32+li32, chunk h
    vf[3] = *(const u16x8*)(vbase + 1024 + 16);   // dv=32+li32, chunk 2+h

    for (int s = 0; s < ns; ++s) {
        u16x8 kn[4], vn[4];
        if (s + 1 < ns) {
            const unsigned short* kb2 = kbase + (size_t)(s + 1) * 2048;
            const unsigned short* vb2 = vbase + (size_t)(s + 1) * 2048;
#pragma unroll
            for (int ks = 0; ks < 4; ++ks) kn[ks] = *(const u16x8*)(kb2 + ks * 16);
            vn[0] = *(const u16x8*)(vb2);
            vn[1] = *(const u16x8*)(vb2 + 16);
            vn[2] = *(const u16x8*)(vb2 + 1024);
            vn[3] = *(const u16x8*)(vb2 + 1024 + 16);
        }

        // ---- S^T = K * Q^T (C init = -8: fixed softmax base) ----
        f32x16 sa;
#pragma unroll
        for (int r = 0; r < 16; ++r) sa[r] = -8.0f;
#pragma unroll
        for (int ks = 0; ks < 4; ++ks)
            sa = __builtin_amdgcn_mfma_f32_32x32x16_bf16(
                __builtin_bit_cast(bf16x8, kf[ks]), qf[ks], sa, 0, 0, 0);

        if (s == sdiag) {            // diagonal sub-tile: causal mask
            const int kvbs = kv0 + s * 32;
#pragma unroll
            for (int r = 0; r < 16; ++r) {
                const int kv = kvbs + (r & 3) + ((r >> 2) << 3) + (h << 2);
                sa[r] = (kv > q) ? -1e30f : sa[r];
            }
        }

#pragma unroll
        for (int r = 0; r < 16; ++r) sa[r] = __builtin_amdgcn_exp2f(sa[r]);

        bf16x8 pf0, pf1;
#pragma unroll
        for (int i = 0; i < 8; ++i) { pf0[i] = (__bf16)sa[i]; pf1[i] = (__bf16)sa[8 + i]; }

        // ---- row sums via MFMA (l_acc row layout == O row layout) ----
        l_acc = __builtin_amdgcn_mfma_f32_32x32x16_bf16(pf0, ones, l_acc, 0, 0, 0);
        l_acc = __builtin_amdgcn_mfma_f32_32x32x16_bf16(pf1, ones, l_acc, 0, 0, 0);

        // ---- PV ----
        o0 = __builtin_amdgcn_mfma_f32_32x32x16_bf16(pf0, __builtin_bit_cast(bf16x8, vf[0]), o0, 0, 0, 0);
        o0 = __builtin_amdgcn_mfma_f32_32x32x16_bf16(pf1, __builtin_bit_cast(bf16x8, vf[1]), o0, 0, 0, 0);
        o1 = __builtin_amdgcn_mfma_f32_32x32x16_bf16(pf0, __builtin_bit_cast(bf16x8, vf[2]), o1, 0, 0, 0);
        o1 = __builtin_amdgcn_mfma_f32_32x32x16_bf16(pf1, __builtin_bit_cast(bf16x8, vf[3]), o1, 0, 0, 0);

        if (s + 1 < ns) {
#pragma unroll
            for (int i = 0; i < 4; ++i) { kf[i] = kn[i]; vf[i] = vn[i]; }
        }
    }

    // ---- epilogue.  O C/D: col = dv, row = (r&3)+8*(r>>2)+4h (same as l_acc) ----
    if (g == 0) {                  // single chunk: final output
#pragma unroll
        for (int r = 0; r < 16; ++r) {
            const int row = (r & 3) + ((r >> 2) << 3) + (h << 2);
            const float inv = 1.0f / l_acc[r];
            float* orow = O + ((size_t)b * L_ + q0w + row) * DH;
            orow[li32]      = o0[r] * inv;
            orow[32 + li32] = o1[r] * inv;
        }
    } else {
        const int idx = (b * 32 + qb) * 8 + c;
        unsigned short* po = Op + (size_t)idx * 8192;
        float* lp = Lp + (size_t)idx * 128;
#pragma unroll
        for (int r = 0; r < 16; ++r) {
            const int row = (r & 3) + ((r >> 2) << 3) + (h << 2);
            __hip_bfloat16 h0 = __float2bfloat16(o0[r]);
            __hip_bfloat16 h1 = __float2bfloat16(o1[r]);
            po[(w * 32 + row) * 64 + li32]      = *(unsigned short*)&h0;
            po[(w * 32 + row) * 64 + 32 + li32] = *(unsigned short*)&h1;
            if (li32 == 0) lp[w * 32 + row] = l_acc[r];
        }
    }
}

// ---------------------------------------------------------------------------
// Kernel 3: merge partial chunks (round-5 verified version, unchanged).
// ---------------------------------------------------------------------------
__global__ __launch_bounds__(256) void merge(
    const unsigned short* __restrict__ Op,
    const float* __restrict__ Lp,
    float* __restrict__ O)
{
    const int b  = blockIdx.x & 7;
    const int qb = 4 + (blockIdx.x >> 3);
    const int nc = (qb >> 2) + 1;

    const int row = threadIdx.x >> 1;
    const int c0  = (threadIdx.x & 1) * 32;
    const int idx0 = (b * 32 + qb) * 8;

    float acc[32];
#pragma unroll
    for (int j = 0; j < 32; ++j) acc[j] = 0.0f;
    float Lr = 0.0f;

    for (int cc = 0; cc < nc; ++cc) {
        Lr += Lp[(size_t)(idx0 + cc) * 128 + row];
        const unsigned short* pp = Op + (size_t)(idx0 + cc) * 8192 + row * 64 + c0;
#pragma unroll
        for (int j8 = 0; j8 < 4; ++j8) {
            const u16x8 a = *(const u16x8*)(pp + j8 * 8);
#pragma unroll
            for (int j = 0; j < 8; ++j) {
                const unsigned int ua = ((unsigned int)a[j]) << 16;
                acc[j8 * 8 + j] += __builtin_bit_cast(float, ua);
            }
        }
    }

    const float inv = 1.0f / Lr;
    float* out = O + ((size_t)b * L_ + qb * 128 + row) * DH + c0;
#pragma unroll
    for (int j4 = 0; j4 < 8; ++j4) {
        f32x4 v;
#pragma unroll
        for (int j = 0; j < 4; ++j) v[j] = acc[j4 * 4 + j] * inv;
        *(f32x4*)(out + j4 * 4) = v;
    }
}

// ---------------------------------------------------------------------------
extern "C" void kernel_launch(void* const* d_in, const int* in_sizes, int n_in,
                              void* d_out, int out_size, void* d_ws, size_t ws_size,
                              hipStream_t stream)
{
    const float* x  = (const float*)d_in[0];
    const float* Wq = (const float*)d_in[1];
    const float* bq = (const float*)d_in[2];
    const float* Wk = (const float*)d_in[3];
    const float* bk = (const float*)d_in[4];
    const float* Wv = (const float*)d_in[5];
    const float* bv = (const float*)d_in[6];

    unsigned short* ws16 = (unsigned short*)d_ws;
    unsigned short* qw  = ws16 + QW_OFF;
    unsigned short* kp  = ws16 + KW_OFF;
    unsigned short* vp  = ws16 + VP_OFF;
    unsigned short* Opp = ws16 + OP_OFF;
    float* Lp = (float*)((char*)d_ws + LP_OFFB);

    qkv_proj<<<512, 256, 0, stream>>>(x, Wq, bq, Wk, bk, Wv, bv, qw, kp, vp);
    attn<<<1152, 256, 0, stream>>>(qw, kp, vp, (float*)d_out, Opp, Lp);
    merge<<<224, 256, 0, stream>>>(Opp, Lp, (float*)d_out);
}

// Round 13
// 58.284 us; speedup vs baseline: 1.5946x; 1.5946x over previous
//
#include <hip/hip_runtime.h>
#include <hip/hip_bf16.h>

#define B_  8
#define L_  4096
#define DH  64

typedef __attribute__((ext_vector_type(8)))  __bf16 bf16x8;
typedef __attribute__((ext_vector_type(16))) float  f32x16;
typedef __attribute__((ext_vector_type(4)))  float  f32x4;
typedef __attribute__((ext_vector_type(8)))  unsigned short u16x8;

// workspace offsets (u16 units unless noted)
#define QW_OFF  0u
#define KW_OFF  2097152u      // Kp: fragment-major K images [8][128][4][64][8]
#define VP_OFF  4194304u      // Vp: fragment-major V images [8][128][4][64][8]
#define OP_OFF  6291456u      // bf16 partials [8][32][8][128][64]
#define LP_OFFB 46137344u     // byte offset: f32 l partials [8][32][8][128]

// ---------------------------------------------------------------------------
// Kernel 1: MFMA QKV projection (round-5 verified structure; K/V images
// stored FRAGMENT-MAJOR so attention's per-wave fragment loads are fully
// coalesced 1KB segments).
//   qo row-major [B*L][64]  (pre-scaled by log2e/sqrt(65))
//   Kp 32-sub image: [ks][lane][8], lane=(h<<5)|kv, elem j <-> K[kv][ks*16+h*8+j]
//   Vp 32-sub image: [f][lane][8],  f=(m<<1)|(dv>=32), lane=(h<<5)|(dv&31),
//                    elem j <-> V[kv=m*16+h*4+(j&3)+8*(j>>2)][dv]
//   (so f0=m0/dvlo, f1=m0/dvhi, f2=m1/dvlo, f3=m1/dvhi)
// ---------------------------------------------------------------------------
__global__ __launch_bounds__(256) void qkv_proj(
    const float* __restrict__ x,
    const float* __restrict__ Wq, const float* __restrict__ bq,
    const float* __restrict__ Wk, const float* __restrict__ bk,
    const float* __restrict__ Wv, const float* __restrict__ bv,
    unsigned short* __restrict__ qo,
    unsigned short* __restrict__ Kp,
    unsigned short* __restrict__ Vp)
{
    __shared__ __align__(16) unsigned short xs[64 * 104];
    __shared__ __align__(16) unsigned short wt[64 * 104];
    __shared__ __align__(16) unsigned short bounce[64 * 64];
    __shared__ float bsm[64];

    const int tid = threadIdx.x;
    const int r0  = blockIdx.x * 64;
    const int bb  = r0 >> 12;
    const int l0  = r0 & 4095;

    {   // zero (pads must stay 0 for the k=64..95 MFMA step)
        const u16x8 z = {0,0,0,0,0,0,0,0};
        for (int i = tid; i < (64 * 104) / 8; i += 256) {
            ((u16x8*)xs)[i] = z;  ((u16x8*)wt)[i] = z;
        }
    }
    __syncthreads();

    // stage x -> bf16 LDS, coalesced
    for (int i = tid; i < 64 * 65; i += 256) {
        const int row = i / 65, col = i - row * 65;
        __hip_bfloat16 v = __float2bfloat16(x[(size_t)r0 * 65 + i]);
        xs[row * 104 + col] = *(unsigned short*)&v;
    }

    const float* Wp[3] = {Wq, Wk, Wv};
    const float* bp[3] = {bq, bk, bv};

    const int w = tid >> 6, lane = tid & 63, li = lane & 15, lg = lane >> 4;
    const int rb = w * 16;

#pragma unroll
    for (int p = 0; p < 3; ++p) {
        __syncthreads();                       // prior pass done with wt/bounce
        for (int i = tid; i < 65 * 64; i += 256) {
            const int k = i >> 6, cc = i & 63;
            __hip_bfloat16 v = __float2bfloat16(Wp[p][i]);
            wt[cc * 104 + k] = *(unsigned short*)&v;
        }
        if (tid < 64) bsm[tid] = bp[p][tid];
        __syncthreads();

        f32x4 acc[4];
#pragma unroll
        for (int j = 0; j < 4; ++j) {
            const float bv_ = bsm[j * 16 + li];
            acc[j] = (f32x4){bv_, bv_, bv_, bv_};
        }
#pragma unroll
        for (int ks = 0; ks < 3; ++ks) {
            const bf16x8 a = __builtin_bit_cast(bf16x8,
                *(const u16x8*)&xs[(rb + li) * 104 + ks * 32 + 8 * lg]);
#pragma unroll
            for (int j = 0; j < 4; ++j) {
                const bf16x8 bf = __builtin_bit_cast(bf16x8,
                    *(const u16x8*)&wt[(j * 16 + li) * 104 + ks * 32 + 8 * lg]);
                acc[j] = __builtin_amdgcn_mfma_f32_16x16x32_bf16(a, bf, acc[j], 0, 0, 0);
            }
        }

        // acc -> bounce (bf16), D row = rb + lg*4 + r, col = j*16 + li
        const float scale = (p == 0) ? (1.4426950408889634f / 8.06225774829855f) : 1.0f;
#pragma unroll
        for (int j = 0; j < 4; ++j)
#pragma unroll
            for (int r = 0; r < 4; ++r) {
                __hip_bfloat16 hv = __float2bfloat16(acc[j][r] * scale);
                bounce[(rb + lg * 4 + r) * 64 + j * 16 + li] = *(unsigned short*)&hv;
            }
        __syncthreads();

        if (p == 0) {
            const int row = tid >> 2, col = (tid & 3) * 16;
            unsigned short* op = qo + (size_t)(r0 + row) * 64 + col;
            *(u16x8*)op       = *(const u16x8*)&bounce[row * 64 + col];
            *(u16x8*)(op + 8) = *(const u16x8*)&bounce[row * 64 + col + 8];
        } else if (p == 1) {
            // K fragment-major scatter: piece = K[row][s*8..s*8+7]
#pragma unroll
            for (int e = 0; e < 2; ++e) {
                const int pi = tid * 2 + e;
                const int row = pi >> 3, s = pi & 7;
                const int l = l0 + row;
                const int kv = l & 31;
                const u16x8 piece = *(const u16x8*)&bounce[row * 64 + (s << 3)];
                const int ks = s >> 1, hh = s & 1;
                *(u16x8*)(Kp + (size_t)(bb * 128 + (l >> 5)) * 2048
                          + ks * 512 + (((hh << 5) | kv) << 3)) = piece;
            }
        } else {
            // V fragment-major scatter
#pragma unroll
            for (int e = 0; e < 2; ++e) {
                const int pi = tid * 2 + e;
                const int t32 = pi >> 8, rem = pi & 255;
                const int dv = rem >> 2, cp = rem & 3;
                const int m = cp >> 1, hh = cp & 1;
                u16x8 piece;
#pragma unroll
                for (int j = 0; j < 8; ++j) {
                    const int kv = m * 16 + hh * 4 + (j & 3) + 8 * (j >> 2);
                    piece[j] = bounce[(t32 * 32 + kv) * 64 + dv];
                }
                const int f = (m << 1) | (dv >> 5);
                *(u16x8*)(Vp + (size_t)(bb * 128 + (l0 >> 5) + t32) * 2048
                          + f * 512 + (((hh << 5) | (dv & 31)) << 3)) = piece;
            }
        }
    }
}

// ---------------------------------------------------------------------------
// Kernel 2: causal flash attention — barrier-free, LDS-free, COALESCED.
// 32x32x16 MFMA, fixed softmax base M=8. Block = (b, 128 q, 512-kv chunk),
// 4 autonomous waves x 32 q. Every K/V fragment is one contiguous 1KB
// wave-load from the fragment-major global images (L1/L2-resident, batch
// pinned to XCD by b=blockIdx&7); one-sub register prefetch; no sync at all.
// ---------------------------------------------------------------------------
__global__ __launch_bounds__(256) void attn(
    const unsigned short* __restrict__ Q,
    const unsigned short* __restrict__ Kp,
    const unsigned short* __restrict__ Vp,
    float* __restrict__ O,
    unsigned short* __restrict__ Op,
    float* __restrict__ Lp)
{
    const int tid  = threadIdx.x;
    const int w    = tid >> 6;
    const int lane = tid & 63;
    const int li32 = lane & 31;
    const int h    = lane >> 5;

    const int b = blockIdx.x & 7;
    const int p = 143 - (blockIdx.x >> 3);   // heavy chunks first
    int g = 0;
    while (2 * (g + 1) * (g + 2) <= p) ++g;
    const int id2 = p - 2 * g * (g + 1);
    const int qq  = id2 / (g + 1);
    const int qb  = 4 * g + qq;
    const int c   = id2 - qq * (g + 1);

    const int q0    = qb * 128;
    const int kv0   = c << 9;
    const int kvend = (kv0 + 512 < q0 + 128) ? kv0 + 512 : q0 + 128;
    const int nsub  = (kvend - kv0) >> 5;          // 32-kv sub-tiles in chunk
    const int q0w   = q0 + w * 32;
    const int q     = q0w + li32;
    const int sdiag = (q0w - kv0) >> 5;            // diagonal sub index
    const int ns    = (sdiag + 1 < nsub) ? sdiag + 1 : nsub;

    const size_t base = (size_t)b * L_ * DH;
    // per-lane fragment bases: fragment-major images, 1KB per fragment
    const unsigned short* kbase =
        Kp + ((size_t)(b * 128) + (kv0 >> 5)) * 2048 + lane * 8;
    const unsigned short* vbase =
        Vp + ((size_t)(b * 128) + (kv0 >> 5)) * 2048 + lane * 8;

    // Q fragments: B-operand, col = q, slot (h,j) -> d = ks*16 + h*8 + j
    bf16x8 qf[4];
#pragma unroll
    for (int ks = 0; ks < 4; ++ks)
        qf[ks] = __builtin_bit_cast(bf16x8,
            *(const u16x8*)(Q + base + (size_t)q * DH + ks * 16 + h * 8));

    // all-ones B fragment for the row-sum MFMA
    u16x8 ou;
#pragma unroll
    for (int i = 0; i < 8; ++i) ou[i] = 0x3F80;
    const bf16x8 ones = __builtin_bit_cast(bf16x8, ou);

    f32x16 o0, o1, l_acc;
#pragma unroll
    for (int r = 0; r < 16; ++r) { o0[r] = 0.0f; o1[r] = 0.0f; l_acc[r] = 0.0f; }

    // prefetch sub 0 (coalesced 1KB loads)
    u16x8 kf[4], vf[4];
#pragma unroll
    for (int i = 0; i < 4; ++i) {
        kf[i] = *(const u16x8*)(kbase + i * 512);
        vf[i] = *(const u16x8*)(vbase + i * 512);
    }

    for (int s = 0; s < ns; ++s) {
        u16x8 kn[4], vn[4];
        if (s + 1 < ns) {
            const unsigned short* kb2 = kbase + (size_t)(s + 1) * 2048;
            const unsigned short* vb2 = vbase + (size_t)(s + 1) * 2048;
#pragma unroll
            for (int i = 0; i < 4; ++i) {
                kn[i] = *(const u16x8*)(kb2 + i * 512);
                vn[i] = *(const u16x8*)(vb2 + i * 512);
            }
        }

        // ---- S^T = K * Q^T (C init = -8: fixed softmax base) ----
        f32x16 sa;
#pragma unroll
        for (int r = 0; r < 16; ++r) sa[r] = -8.0f;
#pragma unroll
        for (int ks = 0; ks < 4; ++ks)
            sa = __builtin_amdgcn_mfma_f32_32x32x16_bf16(
                __builtin_bit_cast(bf16x8, kf[ks]), qf[ks], sa, 0, 0, 0);

        if (s == sdiag) {            // diagonal sub-tile: causal mask
            const int kvbs = kv0 + s * 32;
#pragma unroll
            for (int r = 0; r < 16; ++r) {
                const int kv = kvbs + (r & 3) + ((r >> 2) << 3) + (h << 2);
                sa[r] = (kv > q) ? -1e30f : sa[r];
            }
        }

#pragma unroll
        for (int r = 0; r < 16; ++r) sa[r] = __builtin_amdgcn_exp2f(sa[r]);

        bf16x8 pf0, pf1;
#pragma unroll
        for (int i = 0; i < 8; ++i) { pf0[i] = (__bf16)sa[i]; pf1[i] = (__bf16)sa[8 + i]; }

        // ---- row sums via MFMA (l_acc row layout == O row layout) ----
        l_acc = __builtin_amdgcn_mfma_f32_32x32x16_bf16(pf0, ones, l_acc, 0, 0, 0);
        l_acc = __builtin_amdgcn_mfma_f32_32x32x16_bf16(pf1, ones, l_acc, 0, 0, 0);

        // ---- PV.  pf0 = kv 0..15 (m0), pf1 = kv 16..31 (m1).
        //      vf[0]=m0/dvlo, vf[2]=m1/dvlo, vf[1]=m0/dvhi, vf[3]=m1/dvhi ----
        o0 = __builtin_amdgcn_mfma_f32_32x32x16_bf16(pf0, __builtin_bit_cast(bf16x8, vf[0]), o0, 0, 0, 0);
        o0 = __builtin_amdgcn_mfma_f32_32x32x16_bf16(pf1, __builtin_bit_cast(bf16x8, vf[2]), o0, 0, 0, 0);
        o1 = __builtin_amdgcn_mfma_f32_32x32x16_bf16(pf0, __builtin_bit_cast(bf16x8, vf[1]), o1, 0, 0, 0);
        o1 = __builtin_amdgcn_mfma_f32_32x32x16_bf16(pf1, __builtin_bit_cast(bf16x8, vf[3]), o1, 0, 0, 0);

        if (s + 1 < ns) {
#pragma unroll
            for (int i = 0; i < 4; ++i) { kf[i] = kn[i]; vf[i] = vn[i]; }
        }
    }

    // ---- epilogue.  O C/D: col = dv, row = (r&3)+8*(r>>2)+4h (same as l_acc) ----
    if (g == 0) {                  // single chunk: final output
#pragma unroll
        for (int r = 0; r < 16; ++r) {
            const int row = (r & 3) + ((r >> 2) << 3) + (h << 2);
            const float inv = 1.0f / l_acc[r];
            float* orow = O + ((size_t)b * L_ + q0w + row) * DH;
            orow[li32]      = o0[r] * inv;
            orow[32 + li32] = o1[r] * inv;
        }
    } else {
        const int idx = (b * 32 + qb) * 8 + c;
        unsigned short* po = Op + (size_t)idx * 8192;
        float* lp = Lp + (size_t)idx * 128;
#pragma unroll
        for (int r = 0; r < 16; ++r) {
            const int row = (r & 3) + ((r >> 2) << 3) + (h << 2);
            __hip_bfloat16 h0 = __float2bfloat16(o0[r]);
            __hip_bfloat16 h1 = __float2bfloat16(o1[r]);
            po[(w * 32 + row) * 64 + li32]      = *(unsigned short*)&h0;
            po[(w * 32 + row) * 64 + 32 + li32] = *(unsigned short*)&h1;
            if (li32 == 0) lp[w * 32 + row] = l_acc[r];
        }
    }
}

// ---------------------------------------------------------------------------
// Kernel 3: merge partial chunks (round-5 verified version, unchanged).
// ---------------------------------------------------------------------------
__global__ __launch_bounds__(256) void merge(
    const unsigned short* __restrict__ Op,
    const float* __restrict__ Lp,
    float* __restrict__ O)
{
    const int b  = blockIdx.x & 7;
    const int qb = 4 + (blockIdx.x >> 3);
    const int nc = (qb >> 2) + 1;

    const int row = threadIdx.x >> 1;
    const int c0  = (threadIdx.x & 1) * 32;
    const int idx0 = (b * 32 + qb) * 8;

    float acc[32];
#pragma unroll
    for (int j = 0; j < 32; ++j) acc[j] = 0.0f;
    float Lr = 0.0f;

    for (int cc = 0; cc < nc; ++cc) {
        Lr += Lp[(size_t)(idx0 + cc) * 128 + row];
        const unsigned short* pp = Op + (size_t)(idx0 + cc) * 8192 + row * 64 + c0;
#pragma unroll
        for (int j8 = 0; j8 < 4; ++j8) {
            const u16x8 a = *(const u16x8*)(pp + j8 * 8);
#pragma unroll
            for (int j = 0; j < 8; ++j) {
                const unsigned int ua = ((unsigned int)a[j]) << 16;
                acc[j8 * 8 + j] += __builtin_bit_cast(float, ua);
            }
        }
    }

    const float inv = 1.0f / Lr;
    float* out = O + ((size_t)b * L_ + qb * 128 + row) * DH + c0;
#pragma unroll
    for (int j4 = 0; j4 < 8; ++j4) {
        f32x4 v;
#pragma unroll
        for (int j = 0; j < 4; ++j) v[j] = acc[j4 * 4 + j] * inv;
        *(f32x4*)(out + j4 * 4) = v;
    }
}

// ---------------------------------------------------------------------------
extern "C" void kernel_launch(void* const* d_in, const int* in_sizes, int n_in,
                              void* d_out, int out_size, void* d_ws, size_t ws_size,
                              hipStream_t stream)
{
    const float* x  = (const float*)d_in[0];
    const float* Wq = (const float*)d_in[1];
    const float* bq = (const float*)d_in[2];
    const float* Wk = (const float*)d_in[3];
    const float* bk = (const float*)d_in[4];
    const float* Wv = (const float*)d_in[5];
    const float* bv = (const float*)d_in[6];

    unsigned short* ws16 = (unsigned short*)d_ws;
    unsigned short* qw  = ws16 + QW_OFF;
    unsigned short* kp  = ws16 + KW_OFF;
    unsigned short* vp  = ws16 + VP_OFF;
    unsigned short* Opp = ws16 + OP_OFF;
    float* Lp = (float*)((char*)d_ws + LP_OFFB);

    qkv_proj<<<512, 256, 0, stream>>>(x, Wq, bq, Wk, bk, Wv, bv, qw, kp, vp);
    attn<<<1152, 256, 0, stream>>>(qw, kp, vp, (float*)d_out, Opp, Lp);
    merge<<<224, 256, 0, stream>>>(Opp, Lp, (float*)d_out);
}